// Round 2
// baseline (9271.252 us; speedup 1.0000x reference)
//
#include <hip/hip_runtime.h>

// Problem constants
#define B_   128
#define T_   256
#define H_   256
#define E_   300
#define G4_  1024   // 4*H

// ---------------- prep: mask dtype detection + mask/rowtok build ----------------
__global__ void k_detect(const unsigned char* __restrict__ m8, int* __restrict__ flag) {
    int i = blockIdx.x * 256 + threadIdx.x;      // 0..32767
    if ((i & 3) != 0 && m8[i] != 0) atomicOr(flag, 1);   // nonzero off-aligned byte => 1-byte bool layout
}

__global__ void k_prep(const void* __restrict__ mask, const int* __restrict__ tokens,
                       const int* __restrict__ flag, float* __restrict__ maskf,
                       int* __restrict__ rowtok) {
    int i = blockIdx.x * 256 + threadIdx.x;      // i = b*T + t
    int isbyte = *flag;
    int mv = isbyte ? (int)((const unsigned char*)mask)[i] : ((const int*)mask)[i];
    maskf[i] = mv ? 1.f : 0.f;                   // [b][t]
    int b = i >> 8, t = i & 255;
    rowtok[t * B_ + b] = tokens[i];              // row r = t*B + b  -> token
}

// ---------------- generic fp32 tiled GEMM: C = (A@B + bias) * scale ----------------
// A: MxK row-major (optionally row-gathered), B: KxN row-major, C: MxN row-major
template<bool GATHER>
__global__ __launch_bounds__(256) void k_gemm(
    const float* __restrict__ A, const float* __restrict__ Bm,
    const float* __restrict__ bias, float* __restrict__ C,
    int M, int N, int K, const int* __restrict__ rowidx, float scale)
{
    __shared__ __align__(16) float As[16][68];   // [k][m]
    __shared__ __align__(16) float Bs[16][68];   // [k][n]
    const int tid = threadIdx.x;
    const int tx = tid & 15, ty = tid >> 4;
    const int m0 = blockIdx.y * 64, n0 = blockIdx.x * 64;
    float acc[4][4] = {};

    int arow[4];
#pragma unroll
    for (int i = 0; i < 4; ++i) {
        int e = tid + i * 256;
        int ar = e >> 4;
        int r = m0 + ar;
        arow[i] = GATHER ? rowidx[r] : r;
    }

    for (int k0 = 0; k0 < K; k0 += 16) {
#pragma unroll
        for (int i = 0; i < 4; ++i) {
            int e = tid + i * 256;
            int ak = e & 15, ar = e >> 4;
            float vv = 0.f;
            if (k0 + ak < K) vv = A[(size_t)arow[i] * K + k0 + ak];
            As[ak][ar] = vv;
        }
#pragma unroll
        for (int i = 0; i < 4; ++i) {
            int e = tid + i * 256;
            int nc = e & 63, kr = e >> 6;
            float vv = 0.f;
            if (k0 + kr < K) vv = Bm[(size_t)(k0 + kr) * N + n0 + nc];
            Bs[kr][nc] = vv;
        }
        __syncthreads();
#pragma unroll
        for (int kk = 0; kk < 16; ++kk) {
            float4 av = *(const float4*)&As[kk][ty * 4];
            float4 bv = *(const float4*)&Bs[kk][tx * 4];
            float a_[4] = {av.x, av.y, av.z, av.w};
            float b_[4] = {bv.x, bv.y, bv.z, bv.w};
#pragma unroll
            for (int i = 0; i < 4; ++i)
#pragma unroll
                for (int j = 0; j < 4; ++j)
                    acc[i][j] = fmaf(a_[i], b_[j], acc[i][j]);
        }
        __syncthreads();
    }

    float bs_[4] = {0.f, 0.f, 0.f, 0.f};
    if (bias) {
#pragma unroll
        for (int j = 0; j < 4; ++j) bs_[j] = bias[n0 + tx * 4 + j];
    }
#pragma unroll
    for (int i = 0; i < 4; ++i) {
        float4 o;
        o.x = (acc[i][0] + bs_[0]) * scale;
        o.y = (acc[i][1] + bs_[1]) * scale;
        o.z = (acc[i][2] + bs_[2]) * scale;
        o.w = (acc[i][3] + bs_[3]) * scale;
        *(float4*)&C[(size_t)(m0 + ty * 4 + i) * N + n0 + tx * 4] = o;
    }
}

// ---------------- batch-parallel sequential LSTM (no grid sync) ----------------
// One block per batch row; 1024 threads = one per gate-column of 4H.
// xW: [T][B][1024] (pre-projected input + bias), Wh: [256][1024] row-major.
// Thread tid computes y[tid] = sum_k h[k]*Wh[k][tid]; gate exchange via LDS.
__global__ __launch_bounds__(1024, 1) void lstm_batch(
    const float* __restrict__ xW, const float* __restrict__ Wh,
    float* __restrict__ hs)
{
    __shared__ __align__(16) float lwh[32][1024];   // persistent cache: Wh rows 0..31 (128KB)
    __shared__ float hbuf[2][256];
    __shared__ float abuf[1024];
    const int tid = threadIdx.x;
    const int b = blockIdx.x;
    const int g = tid >> 8;          // gate: 0=i 1=f 2=g 3=o (wave-uniform)
    const int j = tid & 255;         // hidden unit

    for (int e = tid; e < 32 * 1024; e += 1024)
        lwh[e >> 10][e & 1023] = Wh[e];
    if (tid < 256) hbuf[0][tid] = 0.f;
    float c = 0.f;
    __syncthreads();

    int cur = 0;
    const float* wglob = Wh + tid;   // column tid, rows 32..255 streamed from L2
    for (int t = 0; t < T_; ++t) {
        const float x = xW[((size_t)t * B_ + b) * G4_ + tid];   // issued early, used late
        const float* hrow = hbuf[cur];
        float a = 0.f;
#pragma unroll
        for (int k = 0; k < 32; ++k)
            a = fmaf(lwh[k][tid], hrow[k], a);
        for (int k0 = 32; k0 < 256; k0 += 16) {
            float w[16];
#pragma unroll
            for (int u = 0; u < 16; ++u) w[u] = wglob[(size_t)(k0 + u) * G4_];
#pragma unroll
            for (int u = 0; u < 16; ++u) a = fmaf(w[u], hrow[k0 + u], a);
        }
        float y = a + x;
        float act = (g == 2) ? tanhf(y) : 1.f / (1.f + __expf(-y));
        abuf[tid] = act;
        __syncthreads();
        if (g == 0) {
            float iv = act;
            float fv = abuf[j + 256], gv = abuf[j + 512], ov = abuf[j + 768];
            c = fmaf(fv, c, iv * gv);
            float hv = ov * tanhf(c);
            hbuf[cur ^ 1][j] = hv;
            hs[((size_t)b * T_ + t) * H_ + j] = hv;
        }
        __syncthreads();
        cur ^= 1;
    }
}

// ---------------- flash-style single-head attention ----------------
// q,k,v: [B][T][H]; maskf: [B][T] (query-row mask); o: [B][T][H]
__global__ __launch_bounds__(256) void k_attn(
    const float* __restrict__ q, const float* __restrict__ kk_,
    const float* __restrict__ v, const float* __restrict__ maskf,
    float* __restrict__ o)
{
    __shared__ __align__(16) float Qs[16][260];
    __shared__ __align__(16) float Ks[16][260];
    __shared__ __align__(16) float Vs[16][260];
    __shared__ float Ss[16][16];
    const int tid = threadIdx.x;
    const int tx = tid & 15, ty = tid >> 4;
    const int b = blockIdx.y, q0 = blockIdx.x * 16;
    const size_t base = (size_t)b * T_ * H_;

    for (int e4 = tid; e4 < 1024; e4 += 256) {
        int r = e4 >> 6, dq = e4 & 63;
        *(float4*)&Qs[r][dq * 4] = *(const float4*)&q[base + (size_t)(q0 + r) * H_ + dq * 4];
    }
    const float mrow = maskf[b * T_ + q0 + ty];
    float m = -1e30f, l = 0.f;
    float acc[16];
#pragma unroll
    for (int i = 0; i < 16; ++i) acc[i] = 0.f;

    for (int kt = 0; kt < 16; ++kt) {
        for (int e4 = tid; e4 < 1024; e4 += 256) {
            int r = e4 >> 6, dq = e4 & 63;
            *(float4*)&Ks[r][dq * 4] = *(const float4*)&kk_[base + (size_t)(kt * 16 + r) * H_ + dq * 4];
            *(float4*)&Vs[r][dq * 4] = *(const float4*)&v  [base + (size_t)(kt * 16 + r) * H_ + dq * 4];
        }
        __syncthreads();
        float s = 0.f;
#pragma unroll 16
        for (int d = 0; d < 256; d += 4) {
            float4 qv = *(const float4*)&Qs[ty][d];
            float4 kv = *(const float4*)&Ks[tx][d];
            s = fmaf(qv.x, kv.x, fmaf(qv.y, kv.y, fmaf(qv.z, kv.z, fmaf(qv.w, kv.w, s))));
        }
        if (mrow == 0.f) s = 0.f;   // masked query row -> all-equal scores -> uniform softmax
        Ss[ty][tx] = s;
        __syncthreads();
        float tmax = -1e30f;
#pragma unroll
        for (int x = 0; x < 16; ++x) tmax = fmaxf(tmax, Ss[ty][x]);
        float mnew = fmaxf(m, tmax);
        float rsc = __expf(m - mnew);
        float w[16], wsum = 0.f;
#pragma unroll
        for (int x = 0; x < 16; ++x) { w[x] = __expf(Ss[ty][x] - mnew); wsum += w[x]; }
        l = l * rsc + wsum; m = mnew;
#pragma unroll
        for (int dd = 0; dd < 16; ++dd) acc[dd] *= rsc;
#pragma unroll
        for (int x = 0; x < 16; ++x) {
            float wx = w[x];
#pragma unroll
            for (int dd = 0; dd < 16; ++dd)
                acc[dd] = fmaf(wx, Vs[x][tx + dd * 16], acc[dd]);
        }
        __syncthreads();
    }
    float inv = 1.f / l;
#pragma unroll
    for (int dd = 0; dd < 16; ++dd)
        o[base + (size_t)(q0 + ty) * H_ + tx + dd * 16] = acc[dd] * inv;
}

// ---------------- FC1 split-K partials: flat(128 x 65536) @ W1(65536 x 100) ----------------
__global__ __launch_bounds__(256) void k_fc1(
    const float* __restrict__ flat, const float* __restrict__ W1, float* __restrict__ part)
{
    __shared__ __align__(16) float Wt[100][260];   // transposed W1 chunk [j][k]
    __shared__ __align__(16) float fs[2][256];
    const int kc = blockIdx.x, tid = threadIdx.x;  // kc in [0,256): k-range [kc*256, kc*256+256)
    for (int e = tid; e < 25600; e += 256) {
        int k = e / 100, j = e - k * 100;
        Wt[j][k] = W1[(size_t)(kc * 256 + k) * 100 + j];
    }
    __syncthreads();
    const int bh = tid / 100, j = tid - bh * 100;
    for (int bb = 0; bb < 64; ++bb) {
        for (int e = tid; e < 512; e += 256) {
            int bi = e >> 8, k = e & 255;
            fs[bi][k] = flat[(size_t)(bb * 2 + bi) * 65536 + kc * 256 + k];
        }
        __syncthreads();
        if (bh < 2) {
            float acc = 0.f;
#pragma unroll 16
            for (int k = 0; k < 256; k += 4) {
                float4 fv = *(const float4*)&fs[bh][k];
                float4 wv = *(const float4*)&Wt[j][k];
                acc = fmaf(fv.x, wv.x, fmaf(fv.y, wv.y, fmaf(fv.z, wv.z, fmaf(fv.w, wv.w, acc))));
            }
            part[(size_t)kc * 12800 + (bb * 2 + bh) * 100 + j] = acc;
        }
        __syncthreads();
    }
}

// ---------------- head: reduce partials + ReLU + logits + softmax ----------------
__global__ __launch_bounds__(128) void k_head(
    const float* __restrict__ part, const float* __restrict__ b1,
    const float* __restrict__ W2, const float* __restrict__ b2, float* __restrict__ out)
{
    __shared__ float h1s[100];
    __shared__ float ls[2];
    const int b = blockIdx.x, tid = threadIdx.x;
    if (tid < 100) {
        float s = 0.f;
        for (int kc = 0; kc < 256; ++kc) s += part[(size_t)kc * 12800 + b * 100 + tid];
        s += b1[tid];
        h1s[tid] = fmaxf(s, 0.f);
    }
    __syncthreads();
    if (tid < 2) {
        float lg = b2[tid];
        for (int j = 0; j < 100; ++j) lg = fmaf(h1s[j], W2[j * 2 + tid], lg);
        ls[tid] = lg;
    }
    __syncthreads();
    if (tid == 0) {
        float mm = fmaxf(ls[0], ls[1]);
        float e0 = __expf(ls[0] - mm), e1 = __expf(ls[1] - mm);
        float inv = 1.f / (e0 + e1);
        out[b * 2 + 0] = e0 * inv;
        out[b * 2 + 1] = e1 * inv;
    }
}

// ---------------- launch ----------------
extern "C" void kernel_launch(void* const* d_in, const int* in_sizes, int n_in,
                              void* d_out, int out_size, void* d_ws, size_t ws_size,
                              hipStream_t stream) {
    (void)in_sizes; (void)n_in; (void)out_size; (void)ws_size;
    const int*   tokens = (const int*)  d_in[0];
    const void*  mask   =               d_in[1];
    const float* emb    = (const float*)d_in[2];
    const float* Wi     = (const float*)d_in[3];
    const float* Wh     = (const float*)d_in[4];
    const float* b_lstm = (const float*)d_in[5];
    const float* Wq     = (const float*)d_in[6];
    const float* bq     = (const float*)d_in[7];
    const float* Wk     = (const float*)d_in[8];
    const float* bk     = (const float*)d_in[9];
    const float* Wv     = (const float*)d_in[10];
    const float* bv     = (const float*)d_in[11];
    const float* Wo     = (const float*)d_in[12];
    const float* bo     = (const float*)d_in[13];
    const float* W1     = (const float*)d_in[14];
    const float* b1     = (const float*)d_in[15];
    const float* W2     = (const float*)d_in[16];
    const float* b2     = (const float*)d_in[17];
    float* out = (float*)d_out;

    float* ws = (float*)d_ws;
    float* xw    = ws;                        // 33,554,432 f  [T][B][1024]
    float* hsb   = xw + 33554432;             //  8,388,608 f  [B][T][H]
    float* hg    = hsb + 8388608;             //     65,536 f  (unused now)
    float* maskf = hg + 65536;                //     32,768 f
    int*   rowtok= (int*)(maskf + 32768);     //     32,768 i
    int*   flag  = rowtok + 32768;            //          1 i
    // region reuse inside xw after LSTM:
    float* qb   = xw;                         // q
    float* kb   = xw + 8388608;               // k  (later: fc1 partials)
    float* vb   = xw + 16777216;              // v
    float* proj = xw + 25165824;              // attn @ Wo  (= "flat")
    float* attn = hsb;                        // attention output overwrites hs
    float* part = kb;                         // 3,276,800 f

    // prep
    hipMemsetAsync(flag, 0, sizeof(int), stream);
    k_detect<<<128, 256, 0, stream>>>((const unsigned char*)mask, flag);
    k_prep<<<128, 256, 0, stream>>>(mask, tokens, flag, maskf, rowtok);

    // xW = gather(emb, tokens) @ Wi + b_lstm     (M=32768, K=300, N=1024)
    k_gemm<true><<<dim3(16, 512), 256, 0, stream>>>(emb, Wi, b_lstm, xw,
                                                    32768, 1024, 300, rowtok, 1.f);

    // LSTM — batch-parallel, one block per batch row, no grid sync
    lstm_batch<<<128, 1024, 0, stream>>>(xw, Wh, hsb);

    // q,k,v projections (q scaled by 1/sqrt(H)=1/16 after bias)
    k_gemm<false><<<dim3(4, 512), 256, 0, stream>>>(hsb, Wq, bq, qb, 32768, 256, 256, nullptr, 0.0625f);
    k_gemm<false><<<dim3(4, 512), 256, 0, stream>>>(hsb, Wk, bk, kb, 32768, 256, 256, nullptr, 1.f);
    k_gemm<false><<<dim3(4, 512), 256, 0, stream>>>(hsb, Wv, bv, vb, 32768, 256, 256, nullptr, 1.f);

    // attention (writes over hs)
    k_attn<<<dim3(16, 128), 256, 0, stream>>>(qb, kb, vb, maskf, attn);

    // output projection: proj = attn @ Wo + bo
    k_gemm<false><<<dim3(4, 512), 256, 0, stream>>>(attn, Wo, bo, proj, 32768, 256, 256, nullptr, 1.f);

    // FC1 split-K partials + head
    k_fc1<<<256, 256, 0, stream>>>(proj, W1, part);
    k_head<<<128, 128, 0, stream>>>(part, b1, W2, b2, out);
}

// Round 3
// 2647.328 us; speedup vs baseline: 3.5021x; 3.5021x over previous
//
#include <hip/hip_runtime.h>
#include <stdint.h>

// Problem constants
#define B_   128
#define T_   256
#define H_   256
#define E_   300
#define G4_  1024   // 4*H

typedef __attribute__((ext_vector_type(8))) short bf16x8s;  // 8 bf16 (4 VGPRs)
typedef __attribute__((ext_vector_type(4))) float f32x4;

__device__ __forceinline__ short f2bf(float f) {
    unsigned u = __builtin_bit_cast(unsigned, f);
    unsigned r = (u + 0x7fffu + ((u >> 16) & 1u)) >> 16;   // RNE
    return (short)r;
}
__device__ __forceinline__ float sigm(float x) { return 1.f / (1.f + __expf(-x)); }
__device__ __forceinline__ float ftanh(float x) {
    float e = __expf(-2.f * x);
    return (1.f - e) / (1.f + e);
}

// ---------------- prep: mask dtype detection + mask/rowtok build ----------------
__global__ void k_detect(const unsigned char* __restrict__ m8, int* __restrict__ flag) {
    int i = blockIdx.x * 256 + threadIdx.x;      // 0..32767
    if ((i & 3) != 0 && m8[i] != 0) atomicOr(flag, 1);   // nonzero off-aligned byte => 1-byte bool layout
}

__global__ void k_prep(const void* __restrict__ mask, const int* __restrict__ tokens,
                       const int* __restrict__ flag, float* __restrict__ maskf,
                       int* __restrict__ rowtok) {
    int i = blockIdx.x * 256 + threadIdx.x;      // i = b*T + t
    int isbyte = *flag;
    int mv = isbyte ? (int)((const unsigned char*)mask)[i] : ((const int*)mask)[i];
    maskf[i] = mv ? 1.f : 0.f;                   // [b][t]
    int b = i >> 8, t = i & 255;
    rowtok[t * B_ + b] = tokens[i];              // row r = t*B + b  -> token
}

// ---------------- Wh -> packed bf16 MFMA B-fragments ----------------
// frag(nt, ks): lane l, elem i  = Wh[ks*32 + (l>>4)*8 + i][nt*16 + (l&15)]
// stored at whp[((nt*8+ks)*64 + l)*8 + i]
__global__ void k_whpack(const float* __restrict__ Wh, short* __restrict__ whp) {
    int frag = blockIdx.x;              // 0..511 = nt*8+ks
    int nt = frag >> 3, ks = frag & 7;
    int l = threadIdx.x;
    int col = nt * 16 + (l & 15);
    int k0 = ks * 32 + (l >> 4) * 8;
    short tmp[8];
#pragma unroll
    for (int i = 0; i < 8; ++i) tmp[i] = f2bf(Wh[(size_t)(k0 + i) * G4_ + col]);
    int4 v;
    __builtin_memcpy(&v, tmp, 16);
    ((int4*)whp)[frag * 64 + l] = v;
}

// ---------------- generic fp32 tiled GEMM: C = (A@B + bias) * scale ----------------
template<bool GATHER>
__global__ __launch_bounds__(256) void k_gemm(
    const float* __restrict__ A, const float* __restrict__ Bm,
    const float* __restrict__ bias, float* __restrict__ C,
    int M, int N, int K, const int* __restrict__ rowidx, float scale)
{
    __shared__ __align__(16) float As[16][68];   // [k][m]
    __shared__ __align__(16) float Bs[16][68];   // [k][n]
    const int tid = threadIdx.x;
    const int tx = tid & 15, ty = tid >> 4;
    const int m0 = blockIdx.y * 64, n0 = blockIdx.x * 64;
    float acc[4][4] = {};

    int arow[4];
#pragma unroll
    for (int i = 0; i < 4; ++i) {
        int e = tid + i * 256;
        int ar = e >> 4;
        int r = m0 + ar;
        arow[i] = GATHER ? rowidx[r] : r;
    }

    for (int k0 = 0; k0 < K; k0 += 16) {
#pragma unroll
        for (int i = 0; i < 4; ++i) {
            int e = tid + i * 256;
            int ak = e & 15, ar = e >> 4;
            float vv = 0.f;
            if (k0 + ak < K) vv = A[(size_t)arow[i] * K + k0 + ak];
            As[ak][ar] = vv;
        }
#pragma unroll
        for (int i = 0; i < 4; ++i) {
            int e = tid + i * 256;
            int nc = e & 63, kr = e >> 6;
            float vv = 0.f;
            if (k0 + kr < K) vv = Bm[(size_t)(k0 + kr) * N + n0 + nc];
            Bs[kr][nc] = vv;
        }
        __syncthreads();
#pragma unroll
        for (int kk = 0; kk < 16; ++kk) {
            float4 av = *(const float4*)&As[kk][ty * 4];
            float4 bv = *(const float4*)&Bs[kk][tx * 4];
            float a_[4] = {av.x, av.y, av.z, av.w};
            float b_[4] = {bv.x, bv.y, bv.z, bv.w};
#pragma unroll
            for (int i = 0; i < 4; ++i)
#pragma unroll
                for (int j = 0; j < 4; ++j)
                    acc[i][j] = fmaf(a_[i], b_[j], acc[i][j]);
        }
        __syncthreads();
    }

    float bs_[4] = {0.f, 0.f, 0.f, 0.f};
    if (bias) {
#pragma unroll
        for (int j = 0; j < 4; ++j) bs_[j] = bias[n0 + tx * 4 + j];
    }
#pragma unroll
    for (int i = 0; i < 4; ++i) {
        float4 o;
        o.x = (acc[i][0] + bs_[0]) * scale;
        o.y = (acc[i][1] + bs_[1]) * scale;
        o.z = (acc[i][2] + bs_[2]) * scale;
        o.w = (acc[i][3] + bs_[3]) * scale;
        *(float4*)&C[(size_t)(m0 + ty * 4 + i) * N + n0 + tx * 4] = o;
    }
}

// ---------------- MFMA LSTM: 8 blocks x 16 batch rows, bf16 ----------------
// xW: [T][B][1024] fp32 (pre-projected input+bias), whp: packed bf16 frags,
// hs: [B][T][H] fp32 out.
// Wave w owns h-units [64w, 64w+64): n-tiles {16g + 4w + m} for g,m in 0..3.
#define LDA_H 264   // padded row stride (bf16 elems) for h LDS buffer

__global__ __launch_bounds__(256, 1) void lstm_mfma(
    const float* __restrict__ xW, const short* __restrict__ whp,
    float* __restrict__ hs)
{
    __shared__ __align__(16) short whc[128 * 64 * 8];     // ks 0..1 cached (128 KB)
    __shared__ __align__(16) short hb[2][16 * LDA_H];     // double-buffered h (bf16)
    const int tid = threadIdx.x;
    const int l = tid & 63;
    const int w = tid >> 6;            // wave 0..3
    const int cl = l & 15;             // A-row (batch) for reads / D-col within tile
    const int rowq = l >> 4;           // batch quad for D rows
    const int col0 = 64 * w;
    const int bbase = blockIdx.x * 16;

    // preload LDS frag cache: frags (nt, ks<2)
    for (int e = tid; e < 128 * 64; e += 256) {       // int4 units
        int frag = e >> 6, q = e & 63;                // frag = nt*2+ks
        int nt = frag >> 1, ks = frag & 1;
        ((int4*)whc)[e] = ((const int4*)whp)[(nt * 8 + ks) * 64 + q];
    }
    for (int e = tid; e < 2 * 16 * LDA_H; e += 256) ((short*)hb)[e] = 0;
    float creg[4][4];
#pragma unroll
    for (int m = 0; m < 4; ++m)
#pragma unroll
        for (int r = 0; r < 4; ++r) creg[m][r] = 0.f;
    __syncthreads();

    for (int t = 0; t < T_; ++t) {
        const short* hbr = hb[t & 1];
        short* hbw = hb[(t + 1) & 1];
        // A-fragments: a[ks] = h[cl][ks*32 + rowq*8 .. +7]
        bf16x8s a[8];
#pragma unroll
        for (int ks = 0; ks < 8; ++ks)
            a[ks] = *(const bf16x8s*)&hbr[cl * LDA_H + ks * 32 + rowq * 8];

        const float* xwt = xW + ((size_t)t * B_ + bbase) * G4_;

#pragma unroll
        for (int m = 0; m < 4; ++m) {
            f32x4 y[4];
            // init from xW (acts as C-in)
#pragma unroll
            for (int g = 0; g < 4; ++g) {
                int col = g * 256 + col0 + m * 16 + cl;
#pragma unroll
                for (int r = 0; r < 4; ++r)
                    y[g][r] = xwt[(size_t)(rowq * 4 + r) * G4_ + col];
            }
            // MFMA over K
#pragma unroll
            for (int g = 0; g < 4; ++g) {
                const int nt = 16 * g + 4 * w + m;
#pragma unroll
                for (int ks = 0; ks < 8; ++ks) {
                    bf16x8s bf;
                    if (ks < 2) bf = *(const bf16x8s*)&whc[((nt * 2 + ks) * 64 + l) * 8];
                    else        bf = *(const bf16x8s*)&whp[((size_t)(nt * 8 + ks) * 64 + l) * 8];
                    y[g] = __builtin_amdgcn_mfma_f32_16x16x32_bf16(a[ks], bf, y[g], 0, 0, 0);
                }
            }
            // activations + c/h update for this m-tile
            const int j = col0 + m * 16 + cl;
#pragma unroll
            for (int r = 0; r < 4; ++r) {
                float iv = sigm(y[0][r]);
                float fv = sigm(y[1][r]);
                float gv = ftanh(y[2][r]);
                float ov = sigm(y[3][r]);
                float c = fmaf(fv, creg[m][r], iv * gv);
                creg[m][r] = c;
                float hv = ov * ftanh(c);
                int b = rowq * 4 + r;
                hbw[b * LDA_H + j] = f2bf(hv);
                hs[((size_t)(bbase + b) * T_ + t) * H_ + j] = hv;
            }
        }
        __syncthreads();
    }
}

// ---------------- flash-style single-head attention ----------------
__global__ __launch_bounds__(256) void k_attn(
    const float* __restrict__ q, const float* __restrict__ kk_,
    const float* __restrict__ v, const float* __restrict__ maskf,
    float* __restrict__ o)
{
    __shared__ __align__(16) float Qs[16][260];
    __shared__ __align__(16) float Ks[16][260];
    __shared__ __align__(16) float Vs[16][260];
    __shared__ float Ss[16][16];
    const int tid = threadIdx.x;
    const int tx = tid & 15, ty = tid >> 4;
    const int b = blockIdx.y, q0 = blockIdx.x * 16;
    const size_t base = (size_t)b * T_ * H_;

    for (int e4 = tid; e4 < 1024; e4 += 256) {
        int r = e4 >> 6, dq = e4 & 63;
        *(float4*)&Qs[r][dq * 4] = *(const float4*)&q[base + (size_t)(q0 + r) * H_ + dq * 4];
    }
    const float mrow = maskf[b * T_ + q0 + ty];
    float m = -1e30f, l = 0.f;
    float acc[16];
#pragma unroll
    for (int i = 0; i < 16; ++i) acc[i] = 0.f;

    for (int kt = 0; kt < 16; ++kt) {
        for (int e4 = tid; e4 < 1024; e4 += 256) {
            int r = e4 >> 6, dq = e4 & 63;
            *(float4*)&Ks[r][dq * 4] = *(const float4*)&kk_[base + (size_t)(kt * 16 + r) * H_ + dq * 4];
            *(float4*)&Vs[r][dq * 4] = *(const float4*)&v  [base + (size_t)(kt * 16 + r) * H_ + dq * 4];
        }
        __syncthreads();
        float s = 0.f;
#pragma unroll 16
        for (int d = 0; d < 256; d += 4) {
            float4 qv = *(const float4*)&Qs[ty][d];
            float4 kv = *(const float4*)&Ks[tx][d];
            s = fmaf(qv.x, kv.x, fmaf(qv.y, kv.y, fmaf(qv.z, kv.z, fmaf(qv.w, kv.w, s))));
        }
        if (mrow == 0.f) s = 0.f;   // masked query row -> uniform softmax
        Ss[ty][tx] = s;
        __syncthreads();
        float tmax = -1e30f;
#pragma unroll
        for (int x = 0; x < 16; ++x) tmax = fmaxf(tmax, Ss[ty][x]);
        float mnew = fmaxf(m, tmax);
        float rsc = __expf(m - mnew);
        float wv[16], wsum = 0.f;
#pragma unroll
        for (int x = 0; x < 16; ++x) { wv[x] = __expf(Ss[ty][x] - mnew); wsum += wv[x]; }
        l = l * rsc + wsum; m = mnew;
#pragma unroll
        for (int dd = 0; dd < 16; ++dd) acc[dd] *= rsc;
#pragma unroll
        for (int x = 0; x < 16; ++x) {
            float wx = wv[x];
#pragma unroll
            for (int dd = 0; dd < 16; ++dd)
                acc[dd] = fmaf(wx, Vs[x][tx + dd * 16], acc[dd]);
        }
        __syncthreads();
    }
    float inv = 1.f / l;
#pragma unroll
    for (int dd = 0; dd < 16; ++dd)
        o[base + (size_t)(q0 + ty) * H_ + tx + dd * 16] = acc[dd] * inv;
}

// ---------------- FC1 split-K partials ----------------
__global__ __launch_bounds__(256) void k_fc1(
    const float* __restrict__ flat, const float* __restrict__ W1, float* __restrict__ part)
{
    __shared__ __align__(16) float Wt[100][260];
    __shared__ __align__(16) float fs[2][256];
    const int kc = blockIdx.x, tid = threadIdx.x;
    for (int e = tid; e < 25600; e += 256) {
        int k = e / 100, j = e - k * 100;
        Wt[j][k] = W1[(size_t)(kc * 256 + k) * 100 + j];
    }
    __syncthreads();
    const int bh = tid / 100, j = tid - bh * 100;
    for (int bb = 0; bb < 64; ++bb) {
        for (int e = tid; e < 512; e += 256) {
            int bi = e >> 8, k = e & 255;
            fs[bi][k] = flat[(size_t)(bb * 2 + bi) * 65536 + kc * 256 + k];
        }
        __syncthreads();
        if (bh < 2) {
            float acc = 0.f;
#pragma unroll 16
            for (int k = 0; k < 256; k += 4) {
                float4 fv = *(const float4*)&fs[bh][k];
                float4 wv = *(const float4*)&Wt[j][k];
                acc = fmaf(fv.x, wv.x, fmaf(fv.y, wv.y, fmaf(fv.z, wv.z, fmaf(fv.w, wv.w, acc))));
            }
            part[(size_t)kc * 12800 + (bb * 2 + bh) * 100 + j] = acc;
        }
        __syncthreads();
    }
}

// ---------------- head ----------------
__global__ __launch_bounds__(128) void k_head(
    const float* __restrict__ part, const float* __restrict__ b1,
    const float* __restrict__ W2, const float* __restrict__ b2, float* __restrict__ out)
{
    __shared__ float h1s[100];
    __shared__ float ls[2];
    const int b = blockIdx.x, tid = threadIdx.x;
    if (tid < 100) {
        float s = 0.f;
        for (int kc = 0; kc < 256; ++kc) s += part[(size_t)kc * 12800 + b * 100 + tid];
        s += b1[tid];
        h1s[tid] = fmaxf(s, 0.f);
    }
    __syncthreads();
    if (tid < 2) {
        float lg = b2[tid];
        for (int j = 0; j < 100; ++j) lg = fmaf(h1s[j], W2[j * 2 + tid], lg);
        ls[tid] = lg;
    }
    __syncthreads();
    if (tid == 0) {
        float mm = fmaxf(ls[0], ls[1]);
        float e0 = __expf(ls[0] - mm), e1 = __expf(ls[1] - mm);
        float inv = 1.f / (e0 + e1);
        out[b * 2 + 0] = e0 * inv;
        out[b * 2 + 1] = e1 * inv;
    }
}

// ---------------- launch ----------------
extern "C" void kernel_launch(void* const* d_in, const int* in_sizes, int n_in,
                              void* d_out, int out_size, void* d_ws, size_t ws_size,
                              hipStream_t stream) {
    (void)in_sizes; (void)n_in; (void)out_size; (void)ws_size;
    const int*   tokens = (const int*)  d_in[0];
    const void*  mask   =               d_in[1];
    const float* emb    = (const float*)d_in[2];
    const float* Wi     = (const float*)d_in[3];
    const float* Wh     = (const float*)d_in[4];
    const float* b_lstm = (const float*)d_in[5];
    const float* Wq     = (const float*)d_in[6];
    const float* bq     = (const float*)d_in[7];
    const float* Wk     = (const float*)d_in[8];
    const float* bk     = (const float*)d_in[9];
    const float* Wv     = (const float*)d_in[10];
    const float* bv     = (const float*)d_in[11];
    const float* Wo     = (const float*)d_in[12];
    const float* bo     = (const float*)d_in[13];
    const float* W1     = (const float*)d_in[14];
    const float* b1     = (const float*)d_in[15];
    const float* W2     = (const float*)d_in[16];
    const float* b2     = (const float*)d_in[17];
    float* out = (float*)d_out;

    float* ws = (float*)d_ws;
    float* xw    = ws;                        // 33,554,432 f  [T][B][1024]
    float* hsb   = xw + 33554432;             //  8,388,608 f  [B][T][H]
    float* maskf = hsb + 8388608;             //     32,768 f
    int*   rowtok= (int*)(maskf + 32768);     //     32,768 i
    int*   flag  = rowtok + 32768;            //          1 i
    short* whp   = (short*)((((uintptr_t)(flag + 1)) + 255) & ~(uintptr_t)255);  // 262,144 bf16
    // region reuse inside xw after LSTM:
    float* qb   = xw;                         // q
    float* kb   = xw + 8388608;               // k  (later: fc1 partials)
    float* vb   = xw + 16777216;              // v
    float* proj = xw + 25165824;              // attn @ Wo  (= "flat")
    float* attn = hsb;                        // attention output overwrites hs
    float* part = kb;

    // prep
    hipMemsetAsync(flag, 0, sizeof(int), stream);
    k_detect<<<128, 256, 0, stream>>>((const unsigned char*)mask, flag);
    k_prep<<<128, 256, 0, stream>>>(mask, tokens, flag, maskf, rowtok);
    k_whpack<<<512, 64, 0, stream>>>(Wh, whp);

    // xW = gather(emb, tokens) @ Wi + b_lstm     (M=32768, K=300, N=1024)
    k_gemm<true><<<dim3(16, 512), 256, 0, stream>>>(emb, Wi, b_lstm, xw,
                                                    32768, 1024, 300, rowtok, 1.f);

    // LSTM — MFMA, 8 blocks x 16 batch rows, no grid sync
    lstm_mfma<<<8, 256, 0, stream>>>(xw, whp, hsb);

    // q,k,v projections (q scaled by 1/sqrt(H)=1/16 after bias)
    k_gemm<false><<<dim3(4, 512), 256, 0, stream>>>(hsb, Wq, bq, qb, 32768, 256, 256, nullptr, 0.0625f);
    k_gemm<false><<<dim3(4, 512), 256, 0, stream>>>(hsb, Wk, bk, kb, 32768, 256, 256, nullptr, 1.f);
    k_gemm<false><<<dim3(4, 512), 256, 0, stream>>>(hsb, Wv, bv, vb, 32768, 256, 256, nullptr, 1.f);

    // attention (writes over hs)
    k_attn<<<dim3(16, 128), 256, 0, stream>>>(qb, kb, vb, maskf, attn);

    // output projection: proj = attn @ Wo + bo
    k_gemm<false><<<dim3(4, 512), 256, 0, stream>>>(attn, Wo, bo, proj, 32768, 256, 256, nullptr, 1.f);

    // FC1 split-K partials + head
    k_fc1<<<256, 256, 0, stream>>>(proj, W1, part);
    k_head<<<128, 128, 0, stream>>>(part, b1, W2, b2, out);
}